// Round 5
// baseline (134.922 us; speedup 1.0000x reference)
//
#include <hip/hip_runtime.h>
#include <hip/hip_bf16.h>
#include <math.h>

#define B_ 2
#define S_ 2048
#define D_ 1024
#define H_ 16
#define HD_ 64
#define M_ (B_*S_)

typedef __attribute__((ext_vector_type(8))) short bf16x8;
typedef __attribute__((ext_vector_type(4))) float f32x4;

#define MFMA16(a,b,c) __builtin_amdgcn_mfma_f32_16x16x32_bf16(a,b,c,0,0,0)
#define INFF __builtin_inff()

static __device__ __forceinline__ unsigned short f2bf_bits(float f) {
    unsigned int u = __float_as_uint(f);
    unsigned int r = (u + 0x7fffu + ((u >> 16) & 1u)) >> 16;
    return (unsigned short)r;
}

// async global->LDS, 16B per lane; LDS dest = wave-uniform base + lane*16
static __device__ __forceinline__ void gload16(const unsigned short* g, unsigned short* l) {
    __builtin_amdgcn_global_load_lds(
        (const __attribute__((address_space(1))) unsigned int*)(g),
        (__attribute__((address_space(3))) unsigned int*)(l),
        16, 0, 0);
}

// phase end: counted vmcnt published by a raw barrier (no vmcnt(0) drain in loop)
#define PH_END do { \
    asm volatile("s_waitcnt vmcnt(4)" ::: "memory"); \
    __builtin_amdgcn_sched_barrier(0); \
    __builtin_amdgcn_s_barrier(); \
    __builtin_amdgcn_sched_barrier(0); \
} while (0)

// ---------------- prep kernels ----------------
__global__ __launch_bounds__(256) void convert_x_kernel(
    const float* __restrict__ x, unsigned short* __restrict__ o) {
    size_t i = (size_t)blockIdx.x * 256 + threadIdx.x;   // 1M float4s
    float4 v = reinterpret_cast<const float4*>(x)[i];
    ushort4 u;
    u.x = f2bf_bits(v.x); u.y = f2bf_bits(v.y);
    u.z = f2bf_bits(v.z); u.w = f2bf_bits(v.w);
    reinterpret_cast<ushort4*>(o)[i] = u;
}

// W [k][n] f32 -> WT [n][k] bf16 (tiled transpose)
__global__ __launch_bounds__(256) void convw_kernel(
    const float* __restrict__ W0, const float* __restrict__ W1,
    const float* __restrict__ W2, const float* __restrict__ W3,
    unsigned short* __restrict__ OT) {
    __shared__ float t[32][33];
    const float* W = (blockIdx.z == 0) ? W0 : (blockIdx.z == 1) ? W1
                    : (blockIdx.z == 2) ? W2 : W3;
    unsigned short* O = OT + (size_t)blockIdx.z * D_ * D_;
    int tx = threadIdx.x & 31, ty = threadIdx.x >> 5;
    int kb = blockIdx.y * 32, nb = blockIdx.x * 32;
#pragma unroll
    for (int i = 0; i < 4; i++)
        t[ty + 8*i][tx] = W[(size_t)(kb + ty + 8*i) * D_ + nb + tx];
    __syncthreads();
#pragma unroll
    for (int i = 0; i < 4; i++) {
        int n = nb + ty + 8*i, k = kb + tx;
        O[(size_t)n * D_ + k] = f2bf_bits(t[tx][ty + 8*i]);
    }
}

// ---------------- QKV GEMM: 256x256 tile, 8 waves, 4-phase pipelined -------
// C[m][n] = A[m][k]*BT[n][k]^T, K=1024. Grid (16,12): n0<1024: Q (*0.125),
// <2048: K, else V transposed [bh][hd][s]. Full K-tile parity double-buffer;
// per phase: ds_read one half's frags + stage one 16KB half of K-tile t+1 +
// 16 MFMA + vmcnt(4)-before-barrier (counted, never drained in loop).
__global__ __launch_bounds__(512, 2) void gemm_qkv256(
    const unsigned short* __restrict__ A,
    const unsigned short* __restrict__ BT,
    unsigned short* __restrict__ outp)
{
    constexpr int K = 1024;
    __shared__ union {
        struct { unsigned short A[2][2][128*64]; unsigned short B[2][2][128*64]; } s;
        unsigned short vt[256][136];
    } sm;
    const int m0 = blockIdx.x * 256;
    const int n0 = blockIdx.y * 256;
    const int tid = threadIdx.x, lane = tid & 63, wid = tid >> 6;
    const int lrow = lane & 15, lk8 = lane >> 4, orow = lk8 * 4;
    const int wmo = (wid >> 2) * 64;      // m offset within a 128-row half
    const int wno = (wid & 3) * 32;       // n offset within a 128-row half
    const int srow = lane >> 3;           // staging: row within 8-row group
    const int sgr  = lane & 7;            // staging: 16B granule

    f32x4 acc[8][4] = {};
    bf16x8 af[4][2], bf[2][2];

    auto stageA = [&](int par, int mh, int k0) {
#pragma unroll
        for (int j = 0; j < 2; j++) {
            const int rb = wid * 8 + j * 64;
            const int rl = rb + srow;
            const int sc = (sgr ^ (rl & 7)) << 3;
            gload16(A + (size_t)(m0 + mh * 128 + rl) * K + k0 + sc,
                    &sm.s.A[par][mh][rb * 64]);
        }
    };
    auto stageB = [&](int par, int nh, int k0) {
#pragma unroll
        for (int j = 0; j < 2; j++) {
            const int rb = wid * 8 + j * 64;
            const int rl = rb + srow;
            const int sc = (sgr ^ (rl & 7)) << 3;
            gload16(BT + (size_t)(n0 + nh * 128 + rl) * K + k0 + sc,
                    &sm.s.B[par][nh][rb * 64]);
        }
    };
    auto lda = [&](int par, int qm) {
        const unsigned short* ap = &sm.s.A[par][qm][0];
#pragma unroll
        for (int f = 0; f < 4; f++)
#pragma unroll
            for (int ks = 0; ks < 2; ks++) {
                const int rr = wmo + f * 16 + lrow;
                af[f][ks] = *reinterpret_cast<const bf16x8*>(
                    &ap[rr * 64 + (((ks << 2) | lk8) ^ (rr & 7)) * 8]);
            }
    };
    auto ldb = [&](int par, int qn) {
        const unsigned short* bp = &sm.s.B[par][qn][0];
#pragma unroll
        for (int g = 0; g < 2; g++)
#pragma unroll
            for (int ks = 0; ks < 2; ks++) {
                const int rr = wno + g * 16 + lrow;
                bf[g][ks] = *reinterpret_cast<const bf16x8*>(
                    &bp[rr * 64 + (((ks << 2) | lk8) ^ (rr & 7)) * 8]);
            }
    };
    auto mma = [&](int qm, int qn) {
        __builtin_amdgcn_s_setprio(1);
#pragma unroll
        for (int f = 0; f < 4; f++)
#pragma unroll
            for (int g = 0; g < 2; g++)
#pragma unroll
                for (int ks = 0; ks < 2; ks++)
                    acc[qm*4+f][qn*2+g] =
                        MFMA16(af[f][ks], bf[g][ks], acc[qm*4+f][qn*2+g]);
        __builtin_amdgcn_s_setprio(0);
    };

    // prologue: stage K-tile 0 (order matches in-loop coverage analysis)
    stageA(0, 0, 0); stageB(0, 0, 0); stageB(0, 1, 0); stageA(0, 1, 0);
    PH_END;

#pragma unroll 1
    for (int t = 0; t < 16; t++) {
        const int par = t & 1, pn = par ^ 1;
        const int kn = (t < 15) ? (t + 1) * 64 : 0;   // wrap-stage stays in bounds
        lda(par, 0); ldb(par, 0);  stageA(pn, 0, kn);  mma(0, 0);  PH_END;
        ldb(par, 1);               stageB(pn, 0, kn);  mma(0, 1);  PH_END;
        lda(par, 1);               stageB(pn, 1, kn);  mma(1, 1);  PH_END;
        ldb(par, 0);               stageA(pn, 1, kn);  mma(1, 0);  PH_END;
    }

    // drain all in-flight staging before LDS reuse / kernel end
    asm volatile("s_waitcnt vmcnt(0)" ::: "memory");
    __builtin_amdgcn_sched_barrier(0);
    __builtin_amdgcn_s_barrier();

    const int which = n0 >> 10;            // 0=Q 1=K 2=V
    const int nl0 = n0 & 1023;
    const int bq = m0 >> 11;
    unsigned short* obase = outp + (size_t)which * 4194304;

    if (which < 2) {
        const float scale = (which == 0) ? 0.125f : 1.0f;
#pragma unroll
        for (int fi = 0; fi < 8; fi++)
#pragma unroll
            for (int g = 0; g < 4; g++)
#pragma unroll
                for (int r = 0; r < 4; r++) {
                    int m = m0 + (fi >> 2) * 128 + wmo + (fi & 3) * 16 + orow + r;
                    int n = nl0 + (g >> 1) * 128 + wno + (g & 1) * 16 + lrow;
                    int s = m & 2047;
                    obase[(((size_t)(bq * 16 + (n >> 6)) * 2048 + s) << 6) + (n & 63)]
                        = f2bf_bits(acc[fi][g][r] * scale);
                }
    } else {
        // V: 2-pass transpose through (reused) LDS, write [bh][hd][s]
#pragma unroll 1
        for (int qm = 0; qm < 2; qm++) {
#pragma unroll
            for (int f = 0; f < 4; f++)
#pragma unroll
                for (int g = 0; g < 4; g++) {
                    const int ml = wmo + f * 16 + orow;
                    const int nc = (g >> 1) * 128 + wno + (g & 1) * 16 + lrow;
                    uint2 w;
                    w.x = (unsigned)f2bf_bits(acc[qm*4+f][g][0])
                        | ((unsigned)f2bf_bits(acc[qm*4+f][g][1]) << 16);
                    w.y = (unsigned)f2bf_bits(acc[qm*4+f][g][2])
                        | ((unsigned)f2bf_bits(acc[qm*4+f][g][3]) << 16);
                    *reinterpret_cast<uint2*>(&sm.vt[nc][ml]) = w;
                }
            __syncthreads();
            {
                const int row = tid >> 1, c0 = (tid & 1) * 64;
                unsigned short* dst = obase +
                    ((size_t)(bq * 1024) + nl0 + row) * 2048 +
                    (m0 & 2047) + qm * 128 + c0;
#pragma unroll
                for (int j = 0; j < 64; j += 8)
                    *reinterpret_cast<bf16x8*>(dst + j) =
                        *reinterpret_cast<const bf16x8*>(&sm.vt[row][c0 + j]);
            }
            __syncthreads();
        }
    }
}

// ---------------- proj GEMM (128x64 tiles, m97 structure) ------------------
template<int BN, int MODE>
__global__ __launch_bounds__(256) void gemm_gl(
    const unsigned short* __restrict__ A,
    const unsigned short* __restrict__ BT,
    void* __restrict__ outp,
    const float* __restrict__ bias)
{
    constexpr int K = 1024;
    constexpr int NF = (BN == 128) ? 4 : 2;
    __shared__ struct { unsigned short As[128][64]; unsigned short Bs[BN][64]; } sm;
    const int m0 = blockIdx.x * 128;
    const int n0 = blockIdx.y * BN;
    const int tid = threadIdx.x, lane = tid & 63, wid = tid >> 6;
    const int wm = (wid >> 1) * 64;
    const int wn = (wid & 1) * (BN / 2);
    const int lrow = lane & 15, lk8 = lane >> 4, orow = lk8 * 4;
    f32x4 acc[4][NF] = {};

    for (int k0 = 0; k0 < K; k0 += 64) {
#pragma unroll
        for (int i = 0; i < 4; i++) {
            const int rbase = wid * 32 + i * 8;
            const int rl = rbase + (lane >> 3);
            const int sc = ((lane & 7) ^ (rl & 7)) << 3;
            gload16(A + (size_t)(m0 + rl) * K + k0 + sc, &sm.As[rbase][0]);
        }
#pragma unroll
        for (int i = 0; i < BN / 32; i++) {
            const int rbase = wid * (BN / 4) + i * 8;
            const int rl = rbase + (lane >> 3);
            const int sc = ((lane & 7) ^ (rl & 7)) << 3;
            gload16(BT + (size_t)(n0 + rl) * K + k0 + sc, &sm.Bs[rbase][0]);
        }
        __syncthreads();
#pragma unroll
        for (int ks = 0; ks < 2; ks++) {
            bf16x8 af[4], bfr[NF];
#pragma unroll
            for (int f = 0; f < 4; f++) {
                const int row = wm + f * 16 + lrow;
                const int p = (ks * 4 + lk8) ^ (row & 7);
                af[f] = *reinterpret_cast<const bf16x8*>(&sm.As[row][p * 8]);
            }
#pragma unroll
            for (int f = 0; f < NF; f++) {
                const int row = wn + f * 16 + lrow;
                const int p = (ks * 4 + lk8) ^ (row & 7);
                bfr[f] = *reinterpret_cast<const bf16x8*>(&sm.Bs[row][p * 8]);
            }
            __builtin_amdgcn_s_setprio(1);
#pragma unroll
            for (int mf = 0; mf < 4; mf++)
#pragma unroll
                for (int nf = 0; nf < NF; nf++)
                    acc[mf][nf] = MFMA16(af[mf], bfr[nf], acc[mf][nf]);
            __builtin_amdgcn_s_setprio(0);
        }
        __syncthreads();
    }

    float* o = (float*)outp;
#pragma unroll
    for (int mf = 0; mf < 4; mf++)
#pragma unroll
        for (int nf = 0; nf < NF; nf++)
#pragma unroll
            for (int r = 0; r < 4; r++) {
                int m = m0 + wm + mf*16 + orow + r;
                int n = n0 + wn + nf*16 + lrow;
                o[(size_t)m * 1024 + n] = acc[mf][nf][r] + bias[n];
            }
}

// ---------------- flash attention (unchanged from round 4) -----------------
__global__ __launch_bounds__(256) void attn_kernel(
    const unsigned short* __restrict__ Q,   // [bh][s][64]
    const unsigned short* __restrict__ Kb,  // [bh][s][64]
    const unsigned short* __restrict__ VT,  // [bh][64][s]
    unsigned short* __restrict__ ctx)       // [b][s][h*64+hd]
{
    __shared__ unsigned short Ks[2][64][64];
    __shared__ unsigned short Vs[2][64][64];
    __shared__ unsigned short Pl[4][16][72];
    const int fid = blockIdx.x;
    const int xcd = fid & 7, t = fid >> 3;        // t: 0..127
    const int bh = xcd | ((t & 3) << 3);          // 4 bh per XCD
    const int qt = 31 - (t >> 2);                 // longest first
    const int lane = threadIdx.x & 63, wid = threadIdx.x >> 6;
    const int lrow = lane & 15, lk8 = lane >> 4, orow = lk8 * 4;
    const unsigned short* Qp = Q  + (size_t)bh * (S_ * 64);
    const unsigned short* Kp = Kb + (size_t)bh * (S_ * 64);
    const unsigned short* Vp = VT + (size_t)bh * (64 * S_);
    const int b = bh >> 4, h = bh & 15;
    const int q0 = qt * 64 + wid * 16;
    const int nb = qt + 1;

    auto stage = [&](int buf, int kv0) {
#pragma unroll
        for (int i = 0; i < 2; i++) {
            const int rbase = wid * 16 + 8 * i;          // wave-uniform
            const int rl = rbase + (lane >> 3);          // per-lane row
            const int sc = (((lane & 7) ^ (rl & 7)) << 3);
            gload16(Kp + (size_t)(kv0 + rl) * 64 + sc, &Ks[buf][rbase][0]);
            gload16(Vp + (size_t)rl * S_ + kv0 + sc, &Vs[buf][rbase][0]);
        }
    };

    stage(0, 0);

    bf16x8 qf[2];
#pragma unroll
    for (int kt = 0; kt < 2; kt++)
        qf[kt] = *reinterpret_cast<const bf16x8*>(
            Qp + (size_t)(q0 + lrow) * 64 + kt*32 + lk8*8);

    f32x4 acc[4] = {};
    float lr = 0.f;

    __syncthreads();   // drains prologue stage

#pragma unroll 1
    for (int kvb = 0; kvb < nb; kvb++) {
        const int cur = kvb & 1;
        if (kvb + 1 < nb) stage(cur ^ 1, (kvb + 1) * 64);

        // ---- S^T = K·Q^T from swizzled LDS: regs = kv, lane&15 = q ----
        f32x4 sacc[4] = {};
        __builtin_amdgcn_s_setprio(1);
#pragma unroll
        for (int kt = 0; kt < 2; kt++)
#pragma unroll
            for (int nf = 0; nf < 4; nf++) {
                const int row = nf * 16 + lrow;          // kv row
                const int g = ((kt << 2) | lk8) ^ (row & 7);
                bf16x8 kf = *reinterpret_cast<const bf16x8*>(&Ks[cur][row][g << 3]);
                sacc[nf] = MFMA16(kf, qf[kt], sacc[nf]);
            }
        __builtin_amdgcn_s_setprio(0);
        if (kvb == qt) {   // diagonal: mask kv_local > q_local
#pragma unroll
            for (int nf = 0; nf < 4; nf++)
#pragma unroll
                for (int r = 0; r < 4; r++)
                    if (nf*16 + orow + r > wid*16 + lrow) sacc[nf][r] = -INFF;
        }
        // ---- fixed-max softmax: p = exp(s); in-lane partial denominator ----
#pragma unroll
        for (int nf = 0; nf < 4; nf++)
#pragma unroll
            for (int r = 0; r < 4; r++) {
                float p = __expf(sacc[nf][r]);
                sacc[nf][r] = p;
                lr += p;
            }
        // ---- P -> LDS (consecutive kv per lane: packed b64 stores) ----
#pragma unroll
        for (int nf = 0; nf < 4; nf++) {
            uint2 w;
            w.x = (unsigned)f2bf_bits(sacc[nf][0]) | ((unsigned)f2bf_bits(sacc[nf][1]) << 16);
            w.y = (unsigned)f2bf_bits(sacc[nf][2]) | ((unsigned)f2bf_bits(sacc[nf][3]) << 16);
            *reinterpret_cast<uint2*>(&Pl[wid][lrow][nf*16 + orow]) = w;
        }
        bf16x8 pf[2];
#pragma unroll
        for (int kt = 0; kt < 2; kt++)
            pf[kt] = *reinterpret_cast<const bf16x8*>(&Pl[wid][lrow][kt*32 + lk8*8]);
        __builtin_amdgcn_s_setprio(1);
#pragma unroll
        for (int kt = 0; kt < 2; kt++)
#pragma unroll
            for (int nf = 0; nf < 4; nf++) {
                const int row = nf * 16 + lrow;          // hd row of VT
                const int g = ((kt << 2) | lk8) ^ (row & 7);
                bf16x8 vf = *reinterpret_cast<const bf16x8*>(&Vs[cur][row][g << 3]);
                acc[nf] = MFMA16(pf[kt], vf, acc[nf]);
            }
        __builtin_amdgcn_s_setprio(0);
        __syncthreads();  // drains next-tile prefetch; protects buffers
    }

    // ---- epilogue: denominator reduce across lk8 groups, write ctx ----
    lr += __shfl_xor(lr, 16);
    lr += __shfl_xor(lr, 32);
    const float inv = 1.0f / lr;      // all lanes: denom for q = lrow
#pragma unroll
    for (int r = 0; r < 4; r++) {
        const float linv = __shfl(inv, (lane & 48) + orow + r);
#pragma unroll
        for (int nf = 0; nf < 4; nf++) {
            int s = q0 + orow + r;
            int col = h * 64 + nf * 16 + lrow;
            ctx[((size_t)(b * S_ + s)) * D_ + col] = f2bf_bits(acc[nf][r] * linv);
        }
    }
}

// ---------------- launch ----------------
extern "C" void kernel_launch(void* const* d_in, const int* in_sizes, int n_in,
                              void* d_out, int out_size, void* d_ws, size_t ws_size,
                              hipStream_t stream) {
    const float* x  = (const float*)d_in[0];
    const float* Wq = (const float*)d_in[1];
    const float* Wk = (const float*)d_in[2];
    const float* Wv = (const float*)d_in[3];
    const float* Wo = (const float*)d_in[4];
    const float* bo = (const float*)d_in[5];
    float* out = (float*)d_out;

    char* ws = (char*)d_ws;
    unsigned short* xb  = (unsigned short*)(ws);                 // 8 MiB
    unsigned short* WT  = (unsigned short*)(ws + 8388608);       // 4 x 2 MiB
    unsigned short* QKV = (unsigned short*)(ws + 16777216);      // 24 MiB: Q,K,VT
    unsigned short* ctx = (unsigned short*)(ws + 41943040);      // 8 MiB

    unsigned short* Qb  = QKV;
    unsigned short* Kb  = QKV + 4194304;
    unsigned short* VTb = QKV + 8388608;

    convert_x_kernel<<<dim3(4096), dim3(256), 0, stream>>>(x, xb);
    convw_kernel<<<dim3(32, 32, 4), dim3(256), 0, stream>>>(Wq, Wk, Wv, Wo, WT);

    // fused QKV projection: 256x256 tiles, N=3072
    gemm_qkv256<<<dim3(16, 12), dim3(512), 0, stream>>>(xb, WT, QKV);

    attn_kernel<<<dim3(1024), dim3(256), 0, stream>>>(Qb, Kb, VTb, ctx);

    // output projection: N=1024, 128x64 tiles for 512 blocks
    gemm_gl<64, 1><<<dim3(32, 16), dim3(256), 0, stream>>>(
        ctx, WT + 3145728, (void*)out, bo);
}

// Round 6
// 106.025 us; speedup vs baseline: 1.2726x; 1.2726x over previous
//
#include <hip/hip_runtime.h>
#include <hip/hip_bf16.h>
#include <math.h>

#define B_ 2
#define S_ 2048
#define D_ 1024
#define H_ 16
#define HD_ 64
#define M_ (B_*S_)

typedef __attribute__((ext_vector_type(8))) short bf16x8;
typedef __attribute__((ext_vector_type(4))) float f32x4;

#define MFMA16(a,b,c) __builtin_amdgcn_mfma_f32_16x16x32_bf16(a,b,c,0,0,0)
#define INFF __builtin_inff()

static __device__ __forceinline__ unsigned short f2bf_bits(float f) {
    unsigned int u = __float_as_uint(f);
    unsigned int r = (u + 0x7fffu + ((u >> 16) & 1u)) >> 16;
    return (unsigned short)r;
}

// async global->LDS, 16B per lane; LDS dest = wave-uniform base + lane*16
static __device__ __forceinline__ void gload16(const unsigned short* g, unsigned short* l) {
    __builtin_amdgcn_global_load_lds(
        (const __attribute__((address_space(1))) unsigned int*)(g),
        (__attribute__((address_space(3))) unsigned int*)(l),
        16, 0, 0);
}

// phase end: counted vmcnt published by a raw barrier (no vmcnt(0) in loop)
#define PH_END4 do { \
    asm volatile("s_waitcnt vmcnt(4)" ::: "memory"); \
    __builtin_amdgcn_sched_barrier(0); \
    __builtin_amdgcn_s_barrier(); \
    __builtin_amdgcn_sched_barrier(0); \
} while (0)
#define PH_END6 do { \
    asm volatile("s_waitcnt vmcnt(6)" ::: "memory"); \
    __builtin_amdgcn_sched_barrier(0); \
    __builtin_amdgcn_s_barrier(); \
    __builtin_amdgcn_sched_barrier(0); \
} while (0)

// ---------------- prep kernels ----------------
__global__ __launch_bounds__(256) void convert_x_kernel(
    const float* __restrict__ x, unsigned short* __restrict__ o) {
    size_t i = (size_t)blockIdx.x * 256 + threadIdx.x;   // 1M float4s
    float4 v = reinterpret_cast<const float4*>(x)[i];
    ushort4 u;
    u.x = f2bf_bits(v.x); u.y = f2bf_bits(v.y);
    u.z = f2bf_bits(v.z); u.w = f2bf_bits(v.w);
    reinterpret_cast<ushort4*>(o)[i] = u;
}

// W [k][n] f32 -> WT [n][k] bf16 (tiled transpose)
__global__ __launch_bounds__(256) void convw_kernel(
    const float* __restrict__ W0, const float* __restrict__ W1,
    const float* __restrict__ W2, const float* __restrict__ W3,
    unsigned short* __restrict__ OT) {
    __shared__ float t[32][33];
    const float* W = (blockIdx.z == 0) ? W0 : (blockIdx.z == 1) ? W1
                    : (blockIdx.z == 2) ? W2 : W3;
    unsigned short* O = OT + (size_t)blockIdx.z * D_ * D_;
    int tx = threadIdx.x & 31, ty = threadIdx.x >> 5;
    int kb = blockIdx.y * 32, nb = blockIdx.x * 32;
#pragma unroll
    for (int i = 0; i < 4; i++)
        t[ty + 8*i][tx] = W[(size_t)(kb + ty + 8*i) * D_ + nb + tx];
    __syncthreads();
#pragma unroll
    for (int i = 0; i < 4; i++) {
        int n = nb + ty + 8*i, k = kb + tx;
        O[(size_t)n * D_ + k] = f2bf_bits(t[tx][ty + 8*i]);
    }
}

// ---------------- QKV GEMM: 256x256 tile, 8 waves, 4-phase pipelined -------
// Stage order per iter t (into parity pn): P1:B0 P2:A0 P3:B1 P4:A1 of t+1.
// Reads per phase: P1:{A0,B0} P2:{B1} P3:{A1} P4:{B0}. FIFO-derived waits:
// vmcnt 4/4/6/4 give each half a 3-4 phase load-to-use lead; never drained.
__global__ __launch_bounds__(512, 2) void gemm_qkv256(
    const unsigned short* __restrict__ A,
    const unsigned short* __restrict__ BT,
    unsigned short* __restrict__ outp)
{
    __shared__ union {
        struct { unsigned short A[2][2][8192]; unsigned short B[2][2][8192]; } s;
        unsigned short vt[256][136];
    } sm;
    const int tid = threadIdx.x, lane = tid & 63, wid = tid >> 6;
    const int lrow = lane & 15, lk8 = lane >> 4, orow = lk8 * 4;
    const int wmo = (wid >> 2) * 64;      // m offset within 128-row half
    const int wno = (wid & 3) * 32;       // n offset within 128-row half
    const int m0 = blockIdx.x * 256, n0 = blockIdx.y * 256;

    // staging constants: 32-bit offsets, swizzle folded in
    const int srow = lane >> 3, sgr = lane & 7;
    const unsigned sgo = (unsigned)(wid * 8 + srow) * 1024u
                       + (unsigned)((sgr ^ srow) << 3);
    const unsigned short* Ag = A  + (unsigned)m0 * 1024u + sgo;
    const unsigned short* Bg = BT + (unsigned)n0 * 1024u + sgo;
    const int ldsrb = wid * 512;          // wave-uniform LDS dest (elems)

    // ds-read constants
    const int sw0 = ((lk8 ^ (lrow & 7)) << 3);
    const int sw1 = (((4 | lk8) ^ (lrow & 7)) << 3);
    int ar[4], br[2];
#pragma unroll
    for (int f = 0; f < 4; f++) ar[f] = (wmo + f * 16 + lrow) * 64;
#pragma unroll
    for (int g = 0; g < 2; g++) br[g] = (wno + g * 16 + lrow) * 64;

    f32x4 acc[8][4] = {};
    bf16x8 af[4][2], bf[2][2];

    auto stA = [&](int par, int mh, unsigned k) {
        unsigned short* d = &sm.s.A[par][mh][ldsrb];
        const unsigned short* g = Ag + (unsigned)mh * 131072u + k;
        gload16(g, d);
        gload16(g + 65536u, d + 4096);
    };
    auto stB = [&](int par, int nh, unsigned k) {
        unsigned short* d = &sm.s.B[par][nh][ldsrb];
        const unsigned short* g = Bg + (unsigned)nh * 131072u + k;
        gload16(g, d);
        gload16(g + 65536u, d + 4096);
    };
    auto lda = [&](int par, int qm) {
        const unsigned short* p = &sm.s.A[par][qm][0];
#pragma unroll
        for (int f = 0; f < 4; f++) {
            af[f][0] = *reinterpret_cast<const bf16x8*>(p + ar[f] + sw0);
            af[f][1] = *reinterpret_cast<const bf16x8*>(p + ar[f] + sw1);
        }
    };
    auto ldb = [&](int par, int qn) {
        const unsigned short* p = &sm.s.B[par][qn][0];
#pragma unroll
        for (int g = 0; g < 2; g++) {
            bf[g][0] = *reinterpret_cast<const bf16x8*>(p + br[g] + sw0);
            bf[g][1] = *reinterpret_cast<const bf16x8*>(p + br[g] + sw1);
        }
    };
    auto mma = [&](int qm, int qn) {
        __builtin_amdgcn_s_setprio(1);
#pragma unroll
        for (int f = 0; f < 4; f++)
#pragma unroll
            for (int g = 0; g < 2; g++)
#pragma unroll
                for (int ks = 0; ks < 2; ks++)
                    acc[qm*4+f][qn*2+g] =
                        MFMA16(af[f][ks], bf[g][ks], acc[qm*4+f][qn*2+g]);
        __builtin_amdgcn_s_setprio(0);
    };

    // prologue: tile 0 in order B0,A0,B1,A1
    stB(0, 0, 0); stA(0, 0, 0); stB(0, 1, 0); stA(0, 1, 0);
    PH_END4;   // B0,A0 landed

#pragma unroll 1
    for (int t = 0; t < 16; t++) {
        const int par = t & 1, pn = par ^ 1;
        const unsigned kn = (t < 15) ? (unsigned)(t + 1) * 64u : 0u;
        lda(par, 0); ldb(par, 0);  stB(pn, 0, kn);  mma(0, 0);  PH_END4;
        ldb(par, 1);               stA(pn, 0, kn);  mma(0, 1);  PH_END4;
        lda(par, 1);               stB(pn, 1, kn);  mma(1, 1);  PH_END6;
        ldb(par, 0);               stA(pn, 1, kn);  mma(1, 0);  PH_END4;
    }

    // drain all in-flight staging before LDS reuse / kernel end
    asm volatile("s_waitcnt vmcnt(0)" ::: "memory");
    __builtin_amdgcn_sched_barrier(0);
    __builtin_amdgcn_s_barrier();

    const int which = n0 >> 10;            // 0=Q 1=K 2=V
    const int nl0 = n0 & 1023;
    const int bq = m0 >> 11;
    unsigned short* obase = outp + (size_t)which * 4194304;

    if (which < 2) {
        const float scale = (which == 0) ? 0.125f : 1.0f;
#pragma unroll
        for (int fi = 0; fi < 8; fi++)
#pragma unroll
            for (int g = 0; g < 4; g++)
#pragma unroll
                for (int r = 0; r < 4; r++) {
                    int m = m0 + (fi >> 2) * 128 + wmo + (fi & 3) * 16 + orow + r;
                    int n = nl0 + (g >> 1) * 128 + wno + (g & 1) * 16 + lrow;
                    int s = m & 2047;
                    obase[(((size_t)(bq * 16 + (n >> 6)) * 2048 + s) << 6) + (n & 63)]
                        = f2bf_bits(acc[fi][g][r] * scale);
                }
    } else {
        // V: 2-pass transpose through reused LDS — qm FULLY UNROLLED so all
        // acc indices are compile-time (rule #20: runtime idx -> scratch)
#pragma unroll
        for (int qm = 0; qm < 2; qm++) {
#pragma unroll
            for (int f = 0; f < 4; f++)
#pragma unroll
                for (int g = 0; g < 4; g++) {
                    const int ml = wmo + f * 16 + orow;
                    const int nc = (g >> 1) * 128 + wno + (g & 1) * 16 + lrow;
                    uint2 w;
                    w.x = (unsigned)f2bf_bits(acc[qm*4+f][g][0])
                        | ((unsigned)f2bf_bits(acc[qm*4+f][g][1]) << 16);
                    w.y = (unsigned)f2bf_bits(acc[qm*4+f][g][2])
                        | ((unsigned)f2bf_bits(acc[qm*4+f][g][3]) << 16);
                    *reinterpret_cast<uint2*>(&sm.vt[nc][ml]) = w;
                }
            __syncthreads();
            {
                const int row = tid >> 1, c0 = (tid & 1) * 64;
                unsigned short* dst = obase +
                    ((size_t)(bq * 1024) + nl0 + row) * 2048 +
                    (m0 & 2047) + qm * 128 + c0;
#pragma unroll
                for (int j = 0; j < 64; j += 8)
                    *reinterpret_cast<bf16x8*>(dst + j) =
                        *reinterpret_cast<const bf16x8*>(&sm.vt[row][c0 + j]);
            }
            __syncthreads();
        }
    }
}

// ---------------- proj GEMM (128x64 tiles, m97 structure) ------------------
template<int BN, int MODE>
__global__ __launch_bounds__(256) void gemm_gl(
    const unsigned short* __restrict__ A,
    const unsigned short* __restrict__ BT,
    void* __restrict__ outp,
    const float* __restrict__ bias)
{
    constexpr int K = 1024;
    constexpr int NF = (BN == 128) ? 4 : 2;
    __shared__ struct { unsigned short As[128][64]; unsigned short Bs[BN][64]; } sm;
    const int m0 = blockIdx.x * 128;
    const int n0 = blockIdx.y * BN;
    const int tid = threadIdx.x, lane = tid & 63, wid = tid >> 6;
    const int wm = (wid >> 1) * 64;
    const int wn = (wid & 1) * (BN / 2);
    const int lrow = lane & 15, lk8 = lane >> 4, orow = lk8 * 4;
    f32x4 acc[4][NF] = {};

    for (int k0 = 0; k0 < K; k0 += 64) {
#pragma unroll
        for (int i = 0; i < 4; i++) {
            const int rbase = wid * 32 + i * 8;
            const int rl = rbase + (lane >> 3);
            const int sc = ((lane & 7) ^ (rl & 7)) << 3;
            gload16(A + (size_t)(m0 + rl) * K + k0 + sc, &sm.As[rbase][0]);
        }
#pragma unroll
        for (int i = 0; i < BN / 32; i++) {
            const int rbase = wid * (BN / 4) + i * 8;
            const int rl = rbase + (lane >> 3);
            const int sc = ((lane & 7) ^ (rl & 7)) << 3;
            gload16(BT + (size_t)(n0 + rl) * K + k0 + sc, &sm.Bs[rbase][0]);
        }
        __syncthreads();
#pragma unroll
        for (int ks = 0; ks < 2; ks++) {
            bf16x8 af[4], bfr[NF];
#pragma unroll
            for (int f = 0; f < 4; f++) {
                const int row = wm + f * 16 + lrow;
                const int p = (ks * 4 + lk8) ^ (row & 7);
                af[f] = *reinterpret_cast<const bf16x8*>(&sm.As[row][p * 8]);
            }
#pragma unroll
            for (int f = 0; f < NF; f++) {
                const int row = wn + f * 16 + lrow;
                const int p = (ks * 4 + lk8) ^ (row & 7);
                bfr[f] = *reinterpret_cast<const bf16x8*>(&sm.Bs[row][p * 8]);
            }
            __builtin_amdgcn_s_setprio(1);
#pragma unroll
            for (int mf = 0; mf < 4; mf++)
#pragma unroll
                for (int nf = 0; nf < NF; nf++)
                    acc[mf][nf] = MFMA16(af[mf], bfr[nf], acc[mf][nf]);
            __builtin_amdgcn_s_setprio(0);
        }
        __syncthreads();
    }

    float* o = (float*)outp;
#pragma unroll
    for (int mf = 0; mf < 4; mf++)
#pragma unroll
        for (int nf = 0; nf < NF; nf++)
#pragma unroll
            for (int r = 0; r < 4; r++) {
                int m = m0 + wm + mf*16 + orow + r;
                int n = n0 + wn + nf*16 + lrow;
                o[(size_t)m * 1024 + n] = acc[mf][nf][r] + bias[n];
            }
}

// ---------------- flash attention (unchanged) ------------------------------
__global__ __launch_bounds__(256) void attn_kernel(
    const unsigned short* __restrict__ Q,   // [bh][s][64]
    const unsigned short* __restrict__ Kb,  // [bh][s][64]
    const unsigned short* __restrict__ VT,  // [bh][64][s]
    unsigned short* __restrict__ ctx)       // [b][s][h*64+hd]
{
    __shared__ unsigned short Ks[2][64][64];
    __shared__ unsigned short Vs[2][64][64];
    __shared__ unsigned short Pl[4][16][72];
    const int fid = blockIdx.x;
    const int xcd = fid & 7, t = fid >> 3;        // t: 0..127
    const int bh = xcd | ((t & 3) << 3);          // 4 bh per XCD
    const int qt = 31 - (t >> 2);                 // longest first
    const int lane = threadIdx.x & 63, wid = threadIdx.x >> 6;
    const int lrow = lane & 15, lk8 = lane >> 4, orow = lk8 * 4;
    const unsigned short* Qp = Q  + (size_t)bh * (S_ * 64);
    const unsigned short* Kp = Kb + (size_t)bh * (S_ * 64);
    const unsigned short* Vp = VT + (size_t)bh * (64 * S_);
    const int b = bh >> 4, h = bh & 15;
    const int q0 = qt * 64 + wid * 16;
    const int nb = qt + 1;

    auto stage = [&](int buf, int kv0) {
#pragma unroll
        for (int i = 0; i < 2; i++) {
            const int rbase = wid * 16 + 8 * i;          // wave-uniform
            const int rl = rbase + (lane >> 3);          // per-lane row
            const int sc = (((lane & 7) ^ (rl & 7)) << 3);
            gload16(Kp + (size_t)(kv0 + rl) * 64 + sc, &Ks[buf][rbase][0]);
            gload16(Vp + (size_t)rl * S_ + kv0 + sc, &Vs[buf][rbase][0]);
        }
    };

    stage(0, 0);

    bf16x8 qf[2];
#pragma unroll
    for (int kt = 0; kt < 2; kt++)
        qf[kt] = *reinterpret_cast<const bf16x8*>(
            Qp + (size_t)(q0 + lrow) * 64 + kt*32 + lk8*8);

    f32x4 acc[4] = {};
    float lr = 0.f;

    __syncthreads();   // drains prologue stage

#pragma unroll 1
    for (int kvb = 0; kvb < nb; kvb++) {
        const int cur = kvb & 1;
        if (kvb + 1 < nb) stage(cur ^ 1, (kvb + 1) * 64);

        // ---- S^T = K·Q^T from swizzled LDS: regs = kv, lane&15 = q ----
        f32x4 sacc[4] = {};
        __builtin_amdgcn_s_setprio(1);
#pragma unroll
        for (int kt = 0; kt < 2; kt++)
#pragma unroll
            for (int nf = 0; nf < 4; nf++) {
                const int row = nf * 16 + lrow;          // kv row
                const int g = ((kt << 2) | lk8) ^ (row & 7);
                bf16x8 kf = *reinterpret_cast<const bf16x8*>(&Ks[cur][row][g << 3]);
                sacc[nf] = MFMA16(kf, qf[kt], sacc[nf]);
            }
        __builtin_amdgcn_s_setprio(0);
        if (kvb == qt) {   // diagonal: mask kv_local > q_local
#pragma unroll
            for (int nf = 0; nf < 4; nf++)
#pragma unroll
                for (int r = 0; r < 4; r++)
                    if (nf*16 + orow + r > wid*16 + lrow) sacc[nf][r] = -INFF;
        }
        // ---- fixed-max softmax: p = exp(s); in-lane partial denominator ----
#pragma unroll
        for (int nf = 0; nf < 4; nf++)
#pragma unroll
            for (int r = 0; r < 4; r++) {
                float p = __expf(sacc[nf][r]);
                sacc[nf][r] = p;
                lr += p;
            }
        // ---- P -> LDS (consecutive kv per lane: packed b64 stores) ----
#pragma unroll
        for (int nf = 0; nf < 4; nf++) {
            uint2 w;
            w.x = (unsigned)f2bf_bits(sacc[nf][0]) | ((unsigned)f2bf_bits(sacc[nf][1]) << 16);
            w.y = (unsigned)f2bf_bits(sacc[nf][2]) | ((unsigned)f2bf_bits(sacc[nf][3]) << 16);
            *reinterpret_cast<uint2*>(&Pl[wid][lrow][nf*16 + orow]) = w;
        }
        bf16x8 pf[2];
#pragma unroll
        for (int kt = 0; kt < 2; kt++)
            pf[kt] = *reinterpret_cast<const bf16x8*>(&Pl[wid][lrow][kt*32 + lk8*8]);
        __builtin_amdgcn_s_setprio(1);
#pragma unroll
        for (int kt = 0; kt < 2; kt++)
#pragma unroll
            for (int nf = 0; nf < 4; nf++) {
                const int row = nf * 16 + lrow;          // hd row of VT
                const int g = ((kt << 2) | lk8) ^ (row & 7);
                bf16x8 vf = *reinterpret_cast<const bf16x8*>(&Vs[cur][row][g << 3]);
                acc[nf] = MFMA16(pf[kt], vf, acc[nf]);
            }
        __builtin_amdgcn_s_setprio(0);
        __syncthreads();  // drains next-tile prefetch; protects buffers
    }

    // ---- epilogue: denominator reduce across lk8 groups, write ctx ----
    lr += __shfl_xor(lr, 16);
    lr += __shfl_xor(lr, 32);
    const float inv = 1.0f / lr;      // all lanes: denom for q = lrow
#pragma unroll
    for (int r = 0; r < 4; r++) {
        const float linv = __shfl(inv, (lane & 48) + orow + r);
#pragma unroll
        for (int nf = 0; nf < 4; nf++) {
            int s = q0 + orow + r;
            int col = h * 64 + nf * 16 + lrow;
            ctx[((size_t)(b * S_ + s)) * D_ + col] = f2bf_bits(acc[nf][r] * linv);
        }
    }
}

// ---------------- launch ----------------
extern "C" void kernel_launch(void* const* d_in, const int* in_sizes, int n_in,
                              void* d_out, int out_size, void* d_ws, size_t ws_size,
                              hipStream_t stream) {
    const float* x  = (const float*)d_in[0];
    const float* Wq = (const float*)d_in[1];
    const float* Wk = (const float*)d_in[2];
    const float* Wv = (const float*)d_in[3];
    const float* Wo = (const float*)d_in[4];
    const float* bo = (const float*)d_in[5];
    float* out = (float*)d_out;

    char* ws = (char*)d_ws;
    unsigned short* xb  = (unsigned short*)(ws);                 // 8 MiB
    unsigned short* WT  = (unsigned short*)(ws + 8388608);       // 4 x 2 MiB
    unsigned short* QKV = (unsigned short*)(ws + 16777216);      // 24 MiB: Q,K,VT
    unsigned short* ctx = (unsigned short*)(ws + 41943040);      // 8 MiB

    unsigned short* Qb  = QKV;
    unsigned short* Kb  = QKV + 4194304;
    unsigned short* VTb = QKV + 8388608;

    convert_x_kernel<<<dim3(4096), dim3(256), 0, stream>>>(x, xb);
    convw_kernel<<<dim3(32, 32, 4), dim3(256), 0, stream>>>(Wq, Wk, Wv, Wo, WT);

    // fused QKV projection: 256x256 tiles, N=3072
    gemm_qkv256<<<dim3(16, 12), dim3(512), 0, stream>>>(xb, WT, QKV);

    attn_kernel<<<dim3(1024), dim3(256), 0, stream>>>(Qb, Kb, VTb, ctx);

    // output projection: N=1024, 128x64 tiles for 512 blocks
    gemm_gl<64, 1><<<dim3(32, 16), dim3(256), 0, stream>>>(
        ctx, WT + 3145728, (void*)out, bo);
}

// Round 8
// 101.984 us; speedup vs baseline: 1.3230x; 1.0396x over previous
//
#include <hip/hip_runtime.h>
#include <hip/hip_bf16.h>
#include <math.h>

#define B_ 2
#define S_ 2048
#define D_ 1024
#define H_ 16
#define HD_ 64
#define M_ (B_*S_)

typedef __attribute__((ext_vector_type(8))) short bf16x8;
typedef __attribute__((ext_vector_type(4))) float f32x4;

#define MFMA16(a,b,c) __builtin_amdgcn_mfma_f32_16x16x32_bf16(a,b,c,0,0,0)
#define INFF __builtin_inff()
#define LOG2E 1.44269504088896340736f
#define EXP2F(x) __builtin_amdgcn_exp2f(x)

static __device__ __forceinline__ unsigned short f2bf_bits(float f) {
    unsigned int u = __float_as_uint(f);
    unsigned int r = (u + 0x7fffu + ((u >> 16) & 1u)) >> 16;
    return (unsigned short)r;
}

// pack 2 f32 -> 2 bf16 in one dword (lo=a, hi=b), RNE
static __device__ __forceinline__ unsigned cvt_pk_bf16(float a, float b) {
    unsigned r;
    asm("v_cvt_pk_bf16_f32 %0, %1, %2" : "=v"(r) : "v"(a), "v"(b));
    return r;
}

// async global->LDS, 16B per lane; LDS dest = wave-uniform base + lane*16
static __device__ __forceinline__ void gload16(const unsigned short* g, unsigned short* l) {
    __builtin_amdgcn_global_load_lds(
        (const __attribute__((address_space(1))) unsigned int*)(g),
        (__attribute__((address_space(3))) unsigned int*)(l),
        16, 0, 0);
}

#define PH_WAIT_BAR(N) do { \
    asm volatile("s_waitcnt vmcnt(" #N ")" ::: "memory"); \
    __builtin_amdgcn_sched_barrier(0); \
    __builtin_amdgcn_s_barrier(); \
    __builtin_amdgcn_sched_barrier(0); \
} while (0)
#define PH_BAR do { \
    __builtin_amdgcn_sched_barrier(0); \
    __builtin_amdgcn_s_barrier(); \
    __builtin_amdgcn_sched_barrier(0); \
} while (0)

// ---------------- prep kernels ----------------
__global__ __launch_bounds__(256) void convert_x_kernel(
    const float* __restrict__ x, unsigned short* __restrict__ o) {
    size_t i = (size_t)blockIdx.x * 256 + threadIdx.x;   // 1M float4s
    float4 v = reinterpret_cast<const float4*>(x)[i];
    ushort4 u;
    u.x = f2bf_bits(v.x); u.y = f2bf_bits(v.y);
    u.z = f2bf_bits(v.z); u.w = f2bf_bits(v.w);
    reinterpret_cast<ushort4*>(o)[i] = u;
}

// W [k][n] f32 -> WT [n][k] bf16 (tiled transpose)
__global__ __launch_bounds__(256) void convw_kernel(
    const float* __restrict__ W0, const float* __restrict__ W1,
    const float* __restrict__ W2, const float* __restrict__ W3,
    unsigned short* __restrict__ OT) {
    __shared__ float t[32][33];
    const float* W = (blockIdx.z == 0) ? W0 : (blockIdx.z == 1) ? W1
                    : (blockIdx.z == 2) ? W2 : W3;
    unsigned short* O = OT + (size_t)blockIdx.z * D_ * D_;
    int tx = threadIdx.x & 31, ty = threadIdx.x >> 5;
    int kb = blockIdx.y * 32, nb = blockIdx.x * 32;
#pragma unroll
    for (int i = 0; i < 4; i++)
        t[ty + 8*i][tx] = W[(size_t)(kb + ty + 8*i) * D_ + nb + tx];
    __syncthreads();
#pragma unroll
    for (int i = 0; i < 4; i++) {
        int n = nb + ty + 8*i, k = kb + tx;
        O[(size_t)n * D_ + k] = f2bf_bits(t[tx][ty + 8*i]);
    }
}

// ---------------- QKV GEMM: 256x256 tile, 8 waves, 4-phase pipelined -------
// All 8 half-tile loads of K-tile t+1 issued in P1 of t (burst), FIFO waits
// vmcnt 10/8/-/4: each half gets a 3-5 phase lead; never drained in loop.
__global__ __launch_bounds__(512, 2) void gemm_qkv256(
    const unsigned short* __restrict__ A,
    const unsigned short* __restrict__ BT,
    unsigned short* __restrict__ outp)
{
    __shared__ union {
        struct { unsigned short A[2][2][8192]; unsigned short B[2][2][8192]; } s;
        unsigned short vt[256][136];
    } sm;
    const int tid = threadIdx.x, lane = tid & 63, wid = tid >> 6;
    const int lrow = lane & 15, lk8 = lane >> 4, orow = lk8 * 4;
    const int wmo = (wid >> 2) * 64;      // m offset within 128-row half
    const int wno = (wid & 3) * 32;       // n offset within 128-row half
    const int m0 = blockIdx.x * 256, n0 = blockIdx.y * 256;

    // staging constants: 32-bit offsets, swizzle folded in
    const int srow = lane >> 3, sgr = lane & 7;
    const unsigned sgo = (unsigned)(wid * 8 + srow) * 1024u
                       + (unsigned)((sgr ^ srow) << 3);
    const unsigned short* Ag = A  + (unsigned)m0 * 1024u + sgo;
    const unsigned short* Bg = BT + (unsigned)n0 * 1024u + sgo;
    const int ldsrb = wid * 512;          // wave-uniform LDS dest (elems)

    // ds-read constants
    const int sw0 = ((lk8 ^ (lrow & 7)) << 3);
    const int sw1 = (((4 | lk8) ^ (lrow & 7)) << 3);
    int ar[4], br[2];
#pragma unroll
    for (int f = 0; f < 4; f++) ar[f] = (wmo + f * 16 + lrow) * 64;
#pragma unroll
    for (int g = 0; g < 2; g++) br[g] = (wno + g * 16 + lrow) * 64;

    f32x4 acc[8][4] = {};
    bf16x8 af[4][2], bf[2][2];

    auto stA = [&](int par, int mh, unsigned k) {
        unsigned short* d = &sm.s.A[par][mh][ldsrb];
        const unsigned short* g = Ag + (unsigned)mh * 131072u + k;
        gload16(g, d);
        gload16(g + 65536u, d + 4096);
    };
    auto stB = [&](int par, int nh, unsigned k) {
        unsigned short* d = &sm.s.B[par][nh][ldsrb];
        const unsigned short* g = Bg + (unsigned)nh * 131072u + k;
        gload16(g, d);
        gload16(g + 65536u, d + 4096);
    };
    auto lda = [&](int par, int qm) {
        const unsigned short* p = &sm.s.A[par][qm][0];
#pragma unroll
        for (int f = 0; f < 4; f++) {
            af[f][0] = *reinterpret_cast<const bf16x8*>(p + ar[f] + sw0);
            af[f][1] = *reinterpret_cast<const bf16x8*>(p + ar[f] + sw1);
        }
    };
    auto ldb = [&](int par, int qn) {
        const unsigned short* p = &sm.s.B[par][qn][0];
#pragma unroll
        for (int g = 0; g < 2; g++) {
            bf[g][0] = *reinterpret_cast<const bf16x8*>(p + br[g] + sw0);
            bf[g][1] = *reinterpret_cast<const bf16x8*>(p + br[g] + sw1);
        }
    };
    auto mma = [&](int qm, int qn) {
        __builtin_amdgcn_s_setprio(1);
#pragma unroll
        for (int f = 0; f < 4; f++)
#pragma unroll
            for (int g = 0; g < 2; g++)
#pragma unroll
                for (int ks = 0; ks < 2; ks++)
                    acc[qm*4+f][qn*2+g] =
                        MFMA16(af[f][ks], bf[g][ks], acc[qm*4+f][qn*2+g]);
        __builtin_amdgcn_s_setprio(0);
    };

    // prologue: full burst of tile 0 (FIFO: B0,A0,B1,A1)
    stB(0, 0, 0); stA(0, 0, 0); stB(0, 1, 0); stA(0, 1, 0);
    PH_WAIT_BAR(4);   // B0,A0 landed; B1,A1 in flight

#pragma unroll 1
    for (int t = 0; t < 16; t++) {
        const int par = t & 1, pn = par ^ 1;
        const unsigned kn = (t < 15) ? (unsigned)(t + 1) * 64u : 0u;
        lda(par, 0); ldb(par, 0);
        stB(pn, 0, kn); stA(pn, 0, kn); stB(pn, 1, kn); stA(pn, 1, kn);
        mma(0, 0);  PH_WAIT_BAR(10);
        ldb(par, 1);  mma(0, 1);  PH_WAIT_BAR(8);
        lda(par, 1);  mma(1, 1);  PH_BAR;
        ldb(par, 0);  mma(1, 0);  PH_WAIT_BAR(4);
    }

    // drain all in-flight staging before LDS reuse / kernel end
    asm volatile("s_waitcnt vmcnt(0)" ::: "memory");
    __builtin_amdgcn_sched_barrier(0);
    __builtin_amdgcn_s_barrier();

    const int which = n0 >> 10;            // 0=Q 1=K 2=V
    const int nl0 = n0 & 1023;
    const int bq = m0 >> 11;
    unsigned short* obase = outp + (size_t)which * 4194304;

    if (which < 2) {
        // Q gets softmax scale AND exp2 fold: 0.125 * log2(e)
        const float scale = (which == 0) ? (0.125f * LOG2E) : 1.0f;
#pragma unroll
        for (int fi = 0; fi < 8; fi++)
#pragma unroll
            for (int g = 0; g < 4; g++)
#pragma unroll
                for (int r = 0; r < 4; r++) {
                    int m = m0 + (fi >> 2) * 128 + wmo + (fi & 3) * 16 + orow + r;
                    int n = nl0 + (g >> 1) * 128 + wno + (g & 1) * 16 + lrow;
                    int s = m & 2047;
                    obase[(((size_t)(bq * 16 + (n >> 6)) * 2048 + s) << 6) + (n & 63)]
                        = f2bf_bits(acc[fi][g][r] * scale);
                }
    } else {
        // V: 2-pass transpose through reused LDS (qm fully unrolled)
#pragma unroll
        for (int qm = 0; qm < 2; qm++) {
#pragma unroll
            for (int f = 0; f < 4; f++)
#pragma unroll
                for (int g = 0; g < 4; g++) {
                    const int ml = wmo + f * 16 + orow;
                    const int nc = (g >> 1) * 128 + wno + (g & 1) * 16 + lrow;
                    uint2 w;
                    w.x = cvt_pk_bf16(acc[qm*4+f][g][0], acc[qm*4+f][g][1]);
                    w.y = cvt_pk_bf16(acc[qm*4+f][g][2], acc[qm*4+f][g][3]);
                    *reinterpret_cast<uint2*>(&sm.vt[nc][ml]) = w;
                }
            __syncthreads();
            {
                const int row = tid >> 1, c0 = (tid & 1) * 64;
                unsigned short* dst = obase +
                    ((size_t)(bq * 1024) + nl0 + row) * 2048 +
                    (m0 & 2047) + qm * 128 + c0;
#pragma unroll
                for (int j = 0; j < 64; j += 8)
                    *reinterpret_cast<bf16x8*>(dst + j) =
                        *reinterpret_cast<const bf16x8*>(&sm.vt[row][c0 + j]);
            }
            __syncthreads();
        }
    }
}

// ---------------- proj GEMM (128x64 tiles, m97 structure) ------------------
template<int BN, int MODE>
__global__ __launch_bounds__(256) void gemm_gl(
    const unsigned short* __restrict__ A,
    const unsigned short* __restrict__ BT,
    void* __restrict__ outp,
    const float* __restrict__ bias)
{
    constexpr int K = 1024;
    constexpr int NF = (BN == 128) ? 4 : 2;
    __shared__ struct { unsigned short As[128][64]; unsigned short Bs[BN][64]; } sm;
    const int m0 = blockIdx.x * 128;
    const int n0 = blockIdx.y * BN;
    const int tid = threadIdx.x, lane = tid & 63, wid = tid >> 6;
    const int wm = (wid >> 1) * 64;
    const int wn = (wid & 1) * (BN / 2);
    const int lrow = lane & 15, lk8 = lane >> 4, orow = lk8 * 4;
    f32x4 acc[4][NF] = {};

    for (int k0 = 0; k0 < K; k0 += 64) {
#pragma unroll
        for (int i = 0; i < 4; i++) {
            const int rbase = wid * 32 + i * 8;
            const int rl = rbase + (lane >> 3);
            const int sc = ((lane & 7) ^ (rl & 7)) << 3;
            gload16(A + (size_t)(m0 + rl) * K + k0 + sc, &sm.As[rbase][0]);
        }
#pragma unroll
        for (int i = 0; i < BN / 32; i++) {
            const int rbase = wid * (BN / 4) + i * 8;
            const int rl = rbase + (lane >> 3);
            const int sc = ((lane & 7) ^ (rl & 7)) << 3;
            gload16(BT + (size_t)(n0 + rl) * K + k0 + sc, &sm.Bs[rbase][0]);
        }
        __syncthreads();
#pragma unroll
        for (int ks = 0; ks < 2; ks++) {
            bf16x8 af[4], bfr[NF];
#pragma unroll
            for (int f = 0; f < 4; f++) {
                const int row = wm + f * 16 + lrow;
                const int p = (ks * 4 + lk8) ^ (row & 7);
                af[f] = *reinterpret_cast<const bf16x8*>(&sm.As[row][p * 8]);
            }
#pragma unroll
            for (int f = 0; f < NF; f++) {
                const int row = wn + f * 16 + lrow;
                const int p = (ks * 4 + lk8) ^ (row & 7);
                bfr[f] = *reinterpret_cast<const bf16x8*>(&sm.Bs[row][p * 8]);
            }
            __builtin_amdgcn_s_setprio(1);
#pragma unroll
            for (int mf = 0; mf < 4; mf++)
#pragma unroll
                for (int nf = 0; nf < NF; nf++)
                    acc[mf][nf] = MFMA16(af[mf], bfr[nf], acc[mf][nf]);
            __builtin_amdgcn_s_setprio(0);
        }
        __syncthreads();
    }

    float* o = (float*)outp;
#pragma unroll
    for (int mf = 0; mf < 4; mf++)
#pragma unroll
        for (int nf = 0; nf < NF; nf++)
#pragma unroll
            for (int r = 0; r < 4; r++) {
                int m = m0 + wm + mf*16 + orow + r;
                int n = n0 + wn + nf*16 + lrow;
                o[(size_t)m * 1024 + n] = acc[mf][nf][r] + bias[n];
            }
}

// ---------------- flash attention --------------------------------------
// 1024 blocks = 32 q-tiles x 32 bh, XCD-swizzled, longest first.
// Swapped QK^T; fixed-max exp2 softmax (log2e folded into Q scale);
// cvt_pk P-pack; XOR-swizzled P LDS; 40960B LDS -> 4 blocks/CU.
__global__ __launch_bounds__(256, 4) void attn_kernel(
    const unsigned short* __restrict__ Q,   // [bh][s][64]
    const unsigned short* __restrict__ Kb,  // [bh][s][64]
    const unsigned short* __restrict__ VT,  // [bh][64][s]
    unsigned short* __restrict__ ctx)       // [b][s][h*64+hd]
{
    __shared__ unsigned short Ks[2][64][64];
    __shared__ unsigned short Vs[2][64][64];
    __shared__ unsigned short Pl[4][16][64];
    const int fid = blockIdx.x;
    const int xcd = fid & 7, t = fid >> 3;        // t: 0..127
    const int bh = xcd | ((t & 3) << 3);          // 4 bh per XCD
    const int qt = 31 - (t >> 2);                 // longest first
    const int lane = threadIdx.x & 63, wid = threadIdx.x >> 6;
    const int lrow = lane & 15, lk8 = lane >> 4, orow = lk8 * 4;
    const unsigned short* Qp = Q  + (size_t)bh * (S_ * 64);
    const unsigned short* Kp = Kb + (size_t)bh * (S_ * 64);
    const unsigned short* Vp = VT + (size_t)bh * (64 * S_);
    const int b = bh >> 4, h = bh & 15;
    const int q0 = qt * 64 + wid * 16;
    const int nb = qt + 1;
    const int psw = (lrow & 7) << 3;              // P swizzle (elems)

    auto stage = [&](int buf, int kv0) {
#pragma unroll
        for (int i = 0; i < 2; i++) {
            const int rbase = wid * 16 + 8 * i;          // wave-uniform
            const int rl = rbase + (lane >> 3);          // per-lane row
            const int sc = (((lane & 7) ^ (rl & 7)) << 3);
            gload16(Kp + (size_t)(kv0 + rl) * 64 + sc, &Ks[buf][rbase][0]);
            gload16(Vp + (size_t)rl * S_ + kv0 + sc, &Vs[buf][rbase][0]);
        }
    };

    stage(0, 0);

    bf16x8 qf[2];
#pragma unroll
    for (int kt = 0; kt < 2; kt++)
        qf[kt] = *reinterpret_cast<const bf16x8*>(
            Qp + (size_t)(q0 + lrow) * 64 + kt*32 + lk8*8);

    f32x4 acc[4] = {};
    float lr = 0.f;

    __syncthreads();   // drains prologue stage

#pragma unroll 1
    for (int kvb = 0; kvb < nb; kvb++) {
        const int cur = kvb & 1;
        if (kvb + 1 < nb) stage(cur ^ 1, (kvb + 1) * 64);

        // ---- S^T = K·Q^T from swizzled LDS: regs = kv, lane&15 = q ----
        f32x4 sacc[4] = {};
        __builtin_amdgcn_s_setprio(1);
#pragma unroll
        for (int kt = 0; kt < 2; kt++)
#pragma unroll
            for (int nf = 0; nf < 4; nf++) {
                const int row = nf * 16 + lrow;          // kv row
                const int g = ((kt << 2) | lk8) ^ (row & 7);
                bf16x8 kf = *reinterpret_cast<const bf16x8*>(&Ks[cur][row][g << 3]);
                sacc[nf] = MFMA16(kf, qf[kt], sacc[nf]);
            }
        __builtin_amdgcn_s_setprio(0);
        if (kvb == qt) {   // diagonal: mask kv_local > q_local
#pragma unroll
            for (int nf = 0; nf < 4; nf++)
#pragma unroll
                for (int r = 0; r < 4; r++)
                    if (nf*16 + orow + r > wid*16 + lrow) sacc[nf][r] = -INFF;
        }
        // ---- fixed-max softmax: p = exp2(s') (log2e pre-folded in Q) ----
        float ps[4];
#pragma unroll
        for (int nf = 0; nf < 4; nf++) {
#pragma unroll
            for (int r = 0; r < 4; r++)
                sacc[nf][r] = EXP2F(sacc[nf][r]);
            ps[nf] = (sacc[nf][0] + sacc[nf][1]) + (sacc[nf][2] + sacc[nf][3]);
        }
        lr += (ps[0] + ps[1]) + (ps[2] + ps[3]);
        // ---- P -> LDS (packed cvt_pk b64 stores, XOR-swizzled) ----
#pragma unroll
        for (int nf = 0; nf < 4; nf++) {
            uint2 w;
            w.x = cvt_pk_bf16(sacc[nf][0], sacc[nf][1]);
            w.y = cvt_pk_bf16(sacc[nf][2], sacc[nf][3]);
            *reinterpret_cast<uint2*>(&Pl[wid][lrow][(nf*16 + orow) ^ psw]) = w;
        }
        bf16x8 pf[2];
#pragma unroll
        for (int kt = 0; kt < 2; kt++)
            pf[kt] = *reinterpret_cast<const bf16x8*>(
                &Pl[wid][lrow][(kt*32 + lk8*8) ^ psw]);
        __builtin_amdgcn_s_setprio(1);
#pragma unroll
        for (int kt = 0; kt < 2; kt++)
#pragma unroll
            for (int nf = 0; nf < 4; nf++) {
                const int row = nf * 16 + lrow;          // hd row of VT
                const int g = ((kt << 2) | lk8) ^ (row & 7);
                bf16x8 vf = *reinterpret_cast<const bf16x8*>(&Vs[cur][row][g << 3]);
                acc[nf] = MFMA16(pf[kt], vf, acc[nf]);
            }
        __builtin_amdgcn_s_setprio(0);
        __syncthreads();  // drains next-tile prefetch; protects buffers
    }

    // ---- epilogue: denominator reduce across lk8 groups, write ctx ----
    lr += __shfl_xor(lr, 16);
    lr += __shfl_xor(lr, 32);
    const float inv = 1.0f / lr;      // all lanes: denom for q = lrow
#pragma unroll
    for (int r = 0; r < 4; r++) {
        const float linv = __shfl(inv, (lane & 48) + orow + r);
#pragma unroll
        for (int nf = 0; nf < 4; nf++) {
            int s = q0 + orow + r;
            int col = h * 64 + nf * 16 + lrow;
            ctx[((size_t)(b * S_ + s)) * D_ + col] = f2bf_bits(acc[nf][r] * linv);
        }
    }
}

// ---------------- launch ----------------
extern "C" void kernel_launch(void* const* d_in, const int* in_sizes, int n_in,
                              void* d_out, int out_size, void* d_ws, size_t ws_size,
                              hipStream_t stream) {
    const float* x  = (const float*)d_in[0];
    const float* Wq = (const float*)d_in[1];
    const float* Wk = (const float*)d_in[2];
    const float* Wv = (const float*)d_in[3];
    const float* Wo = (const float*)d_in[4];
    const float* bo = (const float*)d_in[5];
    float* out = (float*)d_out;

    char* ws = (char*)d_ws;
    unsigned short* xb  = (unsigned short*)(ws);                 // 8 MiB
    unsigned short* WT  = (unsigned short*)(ws + 8388608);       // 4 x 2 MiB
    unsigned short* QKV = (unsigned short*)(ws + 16777216);      // 24 MiB: Q,K,VT
    unsigned short* ctx = (unsigned short*)(ws + 41943040);      // 8 MiB

    unsigned short* Qb  = QKV;
    unsigned short* Kb  = QKV + 4194304;
    unsigned short* VTb = QKV + 8388608;

    convert_x_kernel<<<dim3(4096), dim3(256), 0, stream>>>(x, xb);
    convw_kernel<<<dim3(32, 32, 4), dim3(256), 0, stream>>>(Wq, Wk, Wv, Wo, WT);

    // fused QKV projection: 256x256 tiles, N=3072
    gemm_qkv256<<<dim3(16, 12), dim3(512), 0, stream>>>(xb, WT, QKV);

    attn_kernel<<<dim3(1024), dim3(256), 0, stream>>>(Qb, Kb, VTb, ctx);

    // output projection: N=1024, 128x64 tiles for 512 blocks
    gemm_gl<64, 1><<<dim3(32, 16), dim3(256), 0, stream>>>(
        ctx, WT + 3145728, (void*)out, bo);
}

// Round 9
// 99.478 us; speedup vs baseline: 1.3563x; 1.0252x over previous
//
#include <hip/hip_runtime.h>
#include <hip/hip_bf16.h>
#include <math.h>

#define B_ 2
#define S_ 2048
#define D_ 1024
#define H_ 16
#define HD_ 64
#define M_ (B_*S_)

typedef __attribute__((ext_vector_type(8))) short bf16x8;
typedef __attribute__((ext_vector_type(4))) float f32x4;

#define MFMA16(a,b,c) __builtin_amdgcn_mfma_f32_16x16x32_bf16(a,b,c,0,0,0)
#define INFF __builtin_inff()
#define LOG2E 1.44269504088896340736f
#define EXP2F(x) __builtin_amdgcn_exp2f(x)

static __device__ __forceinline__ unsigned short f2bf_bits(float f) {
    unsigned int u = __float_as_uint(f);
    unsigned int r = (u + 0x7fffu + ((u >> 16) & 1u)) >> 16;
    return (unsigned short)r;
}

// pack 2 f32 -> 2 bf16 in one dword (lo=a, hi=b), RNE
static __device__ __forceinline__ unsigned cvt_pk_bf16(float a, float b) {
    unsigned r;
    asm("v_cvt_pk_bf16_f32 %0, %1, %2" : "=v"(r) : "v"(a), "v"(b));
    return r;
}

// async global->LDS, 16B per lane; LDS dest = wave-uniform base + lane*16
static __device__ __forceinline__ void gload16(const unsigned short* g, unsigned short* l) {
    __builtin_amdgcn_global_load_lds(
        (const __attribute__((address_space(1))) unsigned int*)(g),
        (__attribute__((address_space(3))) unsigned int*)(l),
        16, 0, 0);
}

#define BARR do { \
    __builtin_amdgcn_sched_barrier(0); \
    __builtin_amdgcn_s_barrier(); \
    __builtin_amdgcn_sched_barrier(0); \
} while (0)
#define LGK0 do { \
    asm volatile("s_waitcnt lgkmcnt(0)" ::: "memory"); \
    __builtin_amdgcn_sched_barrier(0); \
} while (0)
#define LGK8 do { \
    asm volatile("s_waitcnt lgkmcnt(8)" ::: "memory"); \
    __builtin_amdgcn_sched_barrier(0); \
} while (0)
#define VM6 do { \
    asm volatile("s_waitcnt vmcnt(6)" ::: "memory"); \
    __builtin_amdgcn_sched_barrier(0); \
} while (0)

// ---------------- prep kernels ----------------
__global__ __launch_bounds__(256) void convert_x_kernel(
    const float* __restrict__ x, unsigned short* __restrict__ o) {
    size_t i = (size_t)blockIdx.x * 256 + threadIdx.x;   // 1M float4s
    float4 v = reinterpret_cast<const float4*>(x)[i];
    ushort4 u;
    u.x = f2bf_bits(v.x); u.y = f2bf_bits(v.y);
    u.z = f2bf_bits(v.z); u.w = f2bf_bits(v.w);
    reinterpret_cast<ushort4*>(o)[i] = u;
}

// W [k][n] f32 -> WT [n][k] bf16 (tiled transpose)
__global__ __launch_bounds__(256) void convw_kernel(
    const float* __restrict__ W0, const float* __restrict__ W1,
    const float* __restrict__ W2, const float* __restrict__ W3,
    unsigned short* __restrict__ OT) {
    __shared__ float t[32][33];
    const float* W = (blockIdx.z == 0) ? W0 : (blockIdx.z == 1) ? W1
                    : (blockIdx.z == 2) ? W2 : W3;
    unsigned short* O = OT + (size_t)blockIdx.z * D_ * D_;
    int tx = threadIdx.x & 31, ty = threadIdx.x >> 5;
    int kb = blockIdx.y * 32, nb = blockIdx.x * 32;
#pragma unroll
    for (int i = 0; i < 4; i++)
        t[ty + 8*i][tx] = W[(size_t)(kb + ty + 8*i) * D_ + nb + tx];
    __syncthreads();
#pragma unroll
    for (int i = 0; i < 4; i++) {
        int n = nb + ty + 8*i, k = kb + tx;
        O[(size_t)n * D_ + k] = f2bf_bits(t[tx][ty + 8*i]);
    }
}

// ---------------- QKV GEMM: 256x256 tile, 8 waves, m201 8-phase port -------
// Iteration = 2 K-tiles (par0, par1). Per phase: ds_read one subtile, stage
// ONE half-tile (2 gload16) into the slot freed last phase, barrier,
// lgkmcnt(0), 16 MFMA (setprio), barrier. vmcnt(6) only at phases 4 & 8
// (3 half-tiles in flight; 6-7 phase lead per stage; never drained in-loop).
__global__ __launch_bounds__(512, 2) void gemm_qkv256(
    const unsigned short* __restrict__ A,
    const unsigned short* __restrict__ BT,
    unsigned short* __restrict__ outp)
{
    __shared__ union {
        struct { unsigned short A[2][2][8192]; unsigned short B[2][2][8192]; } s;
        unsigned short vt[256][136];
    } sm;
    const int tid = threadIdx.x, lane = tid & 63, wid = tid >> 6;
    const int lrow = lane & 15, lk8 = lane >> 4, orow = lk8 * 4;
    const int wmo = (wid >> 2) * 64;      // m offset within 128-row half
    const int wno = (wid & 3) * 32;       // n offset within 128-row half
    const int m0 = blockIdx.x * 256, n0 = blockIdx.y * 256;

    // staging constants: 32-bit offsets, source-side swizzle folded in
    const int srow = lane >> 3, sgr = lane & 7;
    const unsigned sgo = (unsigned)(wid * 8 + srow) * 1024u
                       + (unsigned)((sgr ^ srow) << 3);
    const unsigned short* Ag = A  + (unsigned)m0 * 1024u + sgo;
    const unsigned short* Bg = BT + (unsigned)n0 * 1024u + sgo;
    const int ldsrb = wid * 512;          // wave-uniform LDS dest (elems)

    // ds-read constants
    const int sw0 = ((lk8 ^ (lrow & 7)) << 3);
    const int sw1 = (((4 | lk8) ^ (lrow & 7)) << 3);
    int ar[4], br[2];
#pragma unroll
    for (int f = 0; f < 4; f++) ar[f] = (wmo + f * 16 + lrow) * 64;
#pragma unroll
    for (int g = 0; g < 2; g++) br[g] = (wno + g * 16 + lrow) * 64;

    f32x4 acc[8][4] = {};
    bf16x8 af[4][2], bf0[2][2], bf1[2][2];

    auto stA = [&](int par, int mh, unsigned k) {
        unsigned short* d = &sm.s.A[par][mh][ldsrb];
        const unsigned short* g = Ag + (unsigned)mh * 131072u + k;
        gload16(g, d);
        gload16(g + 65536u, d + 4096);
    };
    auto stB = [&](int par, int nh, unsigned k) {
        unsigned short* d = &sm.s.B[par][nh][ldsrb];
        const unsigned short* g = Bg + (unsigned)nh * 131072u + k;
        gload16(g, d);
        gload16(g + 65536u, d + 4096);
    };
    auto lda = [&](int par, int mh) {
        const unsigned short* p = &sm.s.A[par][mh][0];
#pragma unroll
        for (int f = 0; f < 4; f++) {
            af[f][0] = *reinterpret_cast<const bf16x8*>(p + ar[f] + sw0);
            af[f][1] = *reinterpret_cast<const bf16x8*>(p + ar[f] + sw1);
        }
    };
    auto ldb0 = [&](int par, int nh) {
        const unsigned short* p = &sm.s.B[par][nh][0];
#pragma unroll
        for (int g = 0; g < 2; g++) {
            bf0[g][0] = *reinterpret_cast<const bf16x8*>(p + br[g] + sw0);
            bf0[g][1] = *reinterpret_cast<const bf16x8*>(p + br[g] + sw1);
        }
    };
    auto ldb1 = [&](int par, int nh) {
        const unsigned short* p = &sm.s.B[par][nh][0];
#pragma unroll
        for (int g = 0; g < 2; g++) {
            bf1[g][0] = *reinterpret_cast<const bf16x8*>(p + br[g] + sw0);
            bf1[g][1] = *reinterpret_cast<const bf16x8*>(p + br[g] + sw1);
        }
    };
    auto MMA0 = [&](int mh) {   // af x bf0 -> quadrant (mh, nh=0)
        __builtin_amdgcn_s_setprio(1);
#pragma unroll
        for (int f = 0; f < 4; f++)
#pragma unroll
            for (int g = 0; g < 2; g++)
#pragma unroll
                for (int ks = 0; ks < 2; ks++)
                    acc[mh*4+f][g] = MFMA16(af[f][ks], bf0[g][ks], acc[mh*4+f][g]);
        __builtin_amdgcn_s_setprio(0);
    };
    auto MMA1 = [&](int mh) {   // af x bf1 -> quadrant (mh, nh=1)
        __builtin_amdgcn_s_setprio(1);
#pragma unroll
        for (int f = 0; f < 4; f++)
#pragma unroll
            for (int g = 0; g < 2; g++)
#pragma unroll
                for (int ks = 0; ks < 2; ks++)
                    acc[mh*4+f][2+g] = MFMA16(af[f][ks], bf1[g][ks], acc[mh*4+f][2+g]);
        __builtin_amdgcn_s_setprio(0);
    };

    // prologue: tile0 complete + tile1 {A0,B0,B1}; A1p1 staged in P1 of iter 0
    stA(0, 0, 0);  stB(0, 0, 0);  stB(0, 1, 0);  stA(0, 1, 0);
    stA(1, 0, 64); stB(1, 0, 64); stB(1, 1, 64);
    VM6; BARR;   // tile0 landed; 3 half-tiles in flight (steady-state entry)

#pragma unroll 1
    for (int i = 0; i < 8; i++) {
        const unsigned kA1 = (unsigned)(2*i + 1) * 64u;
        const unsigned k2  = (unsigned)((2*i + 2) & 15) * 64u;  // wraps safe
        const unsigned k3  = (unsigned)((2*i + 3) & 15) * 64u;
        // -------- K-tile 2i (par0) --------
        // P1
        lda(0, 0); ldb0(0, 0); stA(1, 1, kA1);
        LGK8; BARR; LGK0; MMA0(0); BARR;
        // P2
        ldb1(0, 1); stA(0, 0, k2);
        BARR; LGK0; MMA1(0); BARR;
        // P3
        lda(0, 1); stB(0, 0, k2);
        BARR; LGK0; MMA1(1); BARR;
        // P4
        stB(0, 1, k2);
        VM6; BARR; MMA0(1); BARR;
        // -------- K-tile 2i+1 (par1) --------
        // P5
        lda(1, 0); ldb0(1, 0); stA(0, 1, k2);
        LGK8; BARR; LGK0; MMA0(0); BARR;
        // P6
        ldb1(1, 1); stA(1, 0, k3);
        BARR; LGK0; MMA1(0); BARR;
        // P7
        lda(1, 1); stB(1, 0, k3);
        BARR; LGK0; MMA1(1); BARR;
        // P8
        stB(1, 1, k3);
        VM6; BARR; MMA0(1); BARR;
    }

    // drain all in-flight staging before LDS reuse / kernel end
    asm volatile("s_waitcnt vmcnt(0)" ::: "memory");
    __builtin_amdgcn_sched_barrier(0);
    __builtin_amdgcn_s_barrier();

    const int which = n0 >> 10;            // 0=Q 1=K 2=V
    const int nl0 = n0 & 1023;
    const int bq = m0 >> 11;
    unsigned short* obase = outp + (size_t)which * 4194304;

    if (which < 2) {
        // Q gets softmax scale AND exp2 fold: 0.125 * log2(e)
        const float scale = (which == 0) ? (0.125f * LOG2E) : 1.0f;
#pragma unroll
        for (int fi = 0; fi < 8; fi++)
#pragma unroll
            for (int g = 0; g < 4; g++)
#pragma unroll
                for (int r = 0; r < 4; r++) {
                    int m = m0 + (fi >> 2) * 128 + wmo + (fi & 3) * 16 + orow + r;
                    int n = nl0 + (g >> 1) * 128 + wno + (g & 1) * 16 + lrow;
                    int s = m & 2047;
                    obase[(((size_t)(bq * 16 + (n >> 6)) * 2048 + s) << 6) + (n & 63)]
                        = f2bf_bits(acc[fi][g][r] * scale);
                }
    } else {
        // V: 2-pass transpose through reused LDS (qm fully unrolled)
#pragma unroll
        for (int qm = 0; qm < 2; qm++) {
#pragma unroll
            for (int f = 0; f < 4; f++)
#pragma unroll
                for (int g = 0; g < 4; g++) {
                    const int ml = wmo + f * 16 + orow;
                    const int nc = (g >> 1) * 128 + wno + (g & 1) * 16 + lrow;
                    uint2 w;
                    w.x = cvt_pk_bf16(acc[qm*4+f][g][0], acc[qm*4+f][g][1]);
                    w.y = cvt_pk_bf16(acc[qm*4+f][g][2], acc[qm*4+f][g][3]);
                    *reinterpret_cast<uint2*>(&sm.vt[nc][ml]) = w;
                }
            __syncthreads();
            {
                const int row = tid >> 1, c0 = (tid & 1) * 64;
                unsigned short* dst = obase +
                    ((size_t)(bq * 1024) + nl0 + row) * 2048 +
                    (m0 & 2047) + qm * 128 + c0;
#pragma unroll
                for (int j = 0; j < 64; j += 8)
                    *reinterpret_cast<bf16x8*>(dst + j) =
                        *reinterpret_cast<const bf16x8*>(&sm.vt[row][c0 + j]);
            }
            __syncthreads();
        }
    }
}

// ---------------- proj GEMM (128x64 tiles, m97 structure) ------------------
template<int BN, int MODE>
__global__ __launch_bounds__(256) void gemm_gl(
    const unsigned short* __restrict__ A,
    const unsigned short* __restrict__ BT,
    void* __restrict__ outp,
    const float* __restrict__ bias)
{
    constexpr int K = 1024;
    constexpr int NF = (BN == 128) ? 4 : 2;
    __shared__ struct { unsigned short As[128][64]; unsigned short Bs[BN][64]; } sm;
    const int m0 = blockIdx.x * 128;
    const int n0 = blockIdx.y * BN;
    const int tid = threadIdx.x, lane = tid & 63, wid = tid >> 6;
    const int wm = (wid >> 1) * 64;
    const int wn = (wid & 1) * (BN / 2);
    const int lrow = lane & 15, lk8 = lane >> 4, orow = lk8 * 4;
    f32x4 acc[4][NF] = {};

    for (int k0 = 0; k0 < K; k0 += 64) {
#pragma unroll
        for (int i = 0; i < 4; i++) {
            const int rbase = wid * 32 + i * 8;
            const int rl = rbase + (lane >> 3);
            const int sc = ((lane & 7) ^ (rl & 7)) << 3;
            gload16(A + (size_t)(m0 + rl) * K + k0 + sc, &sm.As[rbase][0]);
        }
#pragma unroll
        for (int i = 0; i < BN / 32; i++) {
            const int rbase = wid * (BN / 4) + i * 8;
            const int rl = rbase + (lane >> 3);
            const int sc = ((lane & 7) ^ (rl & 7)) << 3;
            gload16(BT + (size_t)(n0 + rl) * K + k0 + sc, &sm.Bs[rbase][0]);
        }
        __syncthreads();
#pragma unroll
        for (int ks = 0; ks < 2; ks++) {
            bf16x8 af[4], bfr[NF];
#pragma unroll
            for (int f = 0; f < 4; f++) {
                const int row = wm + f * 16 + lrow;
                const int p = (ks * 4 + lk8) ^ (row & 7);
                af[f] = *reinterpret_cast<const bf16x8*>(&sm.As[row][p * 8]);
            }
#pragma unroll
            for (int f = 0; f < NF; f++) {
                const int row = wn + f * 16 + lrow;
                const int p = (ks * 4 + lk8) ^ (row & 7);
                bfr[f] = *reinterpret_cast<const bf16x8*>(&sm.Bs[row][p * 8]);
            }
            __builtin_amdgcn_s_setprio(1);
#pragma unroll
            for (int mf = 0; mf < 4; mf++)
#pragma unroll
                for (int nf = 0; nf < NF; nf++)
                    acc[mf][nf] = MFMA16(af[mf], bfr[nf], acc[mf][nf]);
            __builtin_amdgcn_s_setprio(0);
        }
        __syncthreads();
    }

    float* o = (float*)outp;
#pragma unroll
    for (int mf = 0; mf < 4; mf++)
#pragma unroll
        for (int nf = 0; nf < NF; nf++)
#pragma unroll
            for (int r = 0; r < 4; r++) {
                int m = m0 + wm + mf*16 + orow + r;
                int n = n0 + wn + nf*16 + lrow;
                o[(size_t)m * 1024 + n] = acc[mf][nf][r] + bias[n];
            }
}

// ---------------- flash attention (unchanged from round 8) -----------------
__global__ __launch_bounds__(256, 4) void attn_kernel(
    const unsigned short* __restrict__ Q,   // [bh][s][64]
    const unsigned short* __restrict__ Kb,  // [bh][s][64]
    const unsigned short* __restrict__ VT,  // [bh][64][s]
    unsigned short* __restrict__ ctx)       // [b][s][h*64+hd]
{
    __shared__ unsigned short Ks[2][64][64];
    __shared__ unsigned short Vs[2][64][64];
    __shared__ unsigned short Pl[4][16][64];
    const int fid = blockIdx.x;
    const int xcd = fid & 7, t = fid >> 3;        // t: 0..127
    const int bh = xcd | ((t & 3) << 3);          // 4 bh per XCD
    const int qt = 31 - (t >> 2);                 // longest first
    const int lane = threadIdx.x & 63, wid = threadIdx.x >> 6;
    const int lrow = lane & 15, lk8 = lane >> 4, orow = lk8 * 4;
    const unsigned short* Qp = Q  + (size_t)bh * (S_ * 64);
    const unsigned short* Kp = Kb + (size_t)bh * (S_ * 64);
    const unsigned short* Vp = VT + (size_t)bh * (64 * S_);
    const int b = bh >> 4, h = bh & 15;
    const int q0 = qt * 64 + wid * 16;
    const int nb = qt + 1;
    const int psw = (lrow & 7) << 3;              // P swizzle (elems)

    auto stage = [&](int buf, int kv0) {
#pragma unroll
        for (int i = 0; i < 2; i++) {
            const int rbase = wid * 16 + 8 * i;          // wave-uniform
            const int rl = rbase + (lane >> 3);          // per-lane row
            const int sc = (((lane & 7) ^ (rl & 7)) << 3);
            gload16(Kp + (size_t)(kv0 + rl) * 64 + sc, &Ks[buf][rbase][0]);
            gload16(Vp + (size_t)rl * S_ + kv0 + sc, &Vs[buf][rbase][0]);
        }
    };

    stage(0, 0);

    bf16x8 qf[2];
#pragma unroll
    for (int kt = 0; kt < 2; kt++)
        qf[kt] = *reinterpret_cast<const bf16x8*>(
            Qp + (size_t)(q0 + lrow) * 64 + kt*32 + lk8*8);

    f32x4 acc[4] = {};
    float lr = 0.f;

    __syncthreads();   // drains prologue stage

#pragma unroll 1
    for (int kvb = 0; kvb < nb; kvb++) {
        const int cur = kvb & 1;
        if (kvb + 1 < nb) stage(cur ^ 1, (kvb + 1) * 64);

        // ---- S^T = K·Q^T from swizzled LDS: regs = kv, lane&15 = q ----
        f32x4 sacc[4] = {};
        __builtin_amdgcn_s_setprio(1);
#pragma unroll
        for (int kt = 0; kt < 2; kt++)
#pragma unroll
            for (int nf = 0; nf < 4; nf++) {
                const int row = nf * 16 + lrow;          // kv row
                const int g = ((kt << 2) | lk8) ^ (row & 7);
                bf16x8 kf = *reinterpret_cast<const bf16x8*>(&Ks[cur][row][g << 3]);
                sacc[nf] = MFMA16(kf, qf[kt], sacc[nf]);
            }
        __builtin_amdgcn_s_setprio(0);
        if (kvb == qt) {   // diagonal: mask kv_local > q_local
#pragma unroll
            for (int nf = 0; nf < 4; nf++)
#pragma unroll
                for (int r = 0; r < 4; r++)
                    if (nf*16 + orow + r > wid*16 + lrow) sacc[nf][r] = -INFF;
        }
        // ---- fixed-max softmax: p = exp2(s') (log2e pre-folded in Q) ----
        float ps[4];
#pragma unroll
        for (int nf = 0; nf < 4; nf++) {
#pragma unroll
            for (int r = 0; r < 4; r++)
                sacc[nf][r] = EXP2F(sacc[nf][r]);
            ps[nf] = (sacc[nf][0] + sacc[nf][1]) + (sacc[nf][2] + sacc[nf][3]);
        }
        lr += (ps[0] + ps[1]) + (ps[2] + ps[3]);
        // ---- P -> LDS (packed cvt_pk b64 stores, XOR-swizzled) ----
#pragma unroll
        for (int nf = 0; nf < 4; nf++) {
            uint2 w;
            w.x = cvt_pk_bf16(sacc[nf][0], sacc[nf][1]);
            w.y = cvt_pk_bf16(sacc[nf][2], sacc[nf][3]);
            *reinterpret_cast<uint2*>(&Pl[wid][lrow][(nf*16 + orow) ^ psw]) = w;
        }
        bf16x8 pf[2];
#pragma unroll
        for (int kt = 0; kt < 2; kt++)
            pf[kt] = *reinterpret_cast<const bf16x8*>(
                &Pl[wid][lrow][(kt*32 + lk8*8) ^ psw]);
        __builtin_amdgcn_s_setprio(1);
#pragma unroll
        for (int kt = 0; kt < 2; kt++)
#pragma unroll
            for (int nf = 0; nf < 4; nf++) {
                const int row = nf * 16 + lrow;          // hd row of VT
                const int g = ((kt << 2) | lk8) ^ (row & 7);
                bf16x8 vf = *reinterpret_cast<const bf16x8*>(&Vs[cur][row][g << 3]);
                acc[nf] = MFMA16(pf[kt], vf, acc[nf]);
            }
        __builtin_amdgcn_s_setprio(0);
        __syncthreads();  // drains next-tile prefetch; protects buffers
    }

    // ---- epilogue: denominator reduce across lk8 groups, write ctx ----
    lr += __shfl_xor(lr, 16);
    lr += __shfl_xor(lr, 32);
    const float inv = 1.0f / lr;      // all lanes: denom for q = lrow
#pragma unroll
    for (int r = 0; r < 4; r++) {
        const float linv = __shfl(inv, (lane & 48) + orow + r);
#pragma unroll
        for (int nf = 0; nf < 4; nf++) {
            int s = q0 + orow + r;
            int col = h * 64 + nf * 16 + lrow;
            ctx[((size_t)(b * S_ + s)) * D_ + col] = f2bf_bits(acc[nf][r] * linv);
        }
    }
}

// ---------------- launch ----------------
extern "C" void kernel_launch(void* const* d_in, const int* in_sizes, int n_in,
                              void* d_out, int out_size, void* d_ws, size_t ws_size,
                              hipStream_t stream) {
    const float* x  = (const float*)d_in[0];
    const float* Wq = (const float*)d_in[1];
    const float* Wk = (const float*)d_in[2];
    const float* Wv = (const float*)d_in[3];
    const float* Wo = (const float*)d_in[4];
    const float* bo = (const float*)d_in[5];
    float* out = (float*)d_out;

    char* ws = (char*)d_ws;
    unsigned short* xb  = (unsigned short*)(ws);                 // 8 MiB
    unsigned short* WT  = (unsigned short*)(ws + 8388608);       // 4 x 2 MiB
    unsigned short* QKV = (unsigned short*)(ws + 16777216);      // 24 MiB: Q,K,VT
    unsigned short* ctx = (unsigned short*)(ws + 41943040);      // 8 MiB

    unsigned short* Qb  = QKV;
    unsigned short* Kb  = QKV + 4194304;
    unsigned short* VTb = QKV + 8388608;

    convert_x_kernel<<<dim3(4096), dim3(256), 0, stream>>>(x, xb);
    convw_kernel<<<dim3(32, 32, 4), dim3(256), 0, stream>>>(Wq, Wk, Wv, Wo, WT);

    // fused QKV projection: 256x256 tiles, N=3072
    gemm_qkv256<<<dim3(16, 12), dim3(512), 0, stream>>>(xb, WT, QKV);

    attn_kernel<<<dim3(1024), dim3(256), 0, stream>>>(Qb, Kb, VTb, ctx);

    // output projection: N=1024, 128x64 tiles for 512 blocks
    gemm_gl<64, 1><<<dim3(32, 16), dim3(256), 0, stream>>>(
        ctx, WT + 3145728, (void*)out, bo);
}